// Round 1
// baseline (305.284 us; speedup 1.0000x reference)
//
#include <hip/hip_runtime.h>
#include <stdint.h>

// ---------------------------------------------------------------------------
// ThreeBodyLayer fused kernel (MI355X / gfx950)
//
// out[b] = 0.5 * sum_{q=0..29} ( h2(q,b) @ W3 + b3 )
//   h1 = softplus(u_b + a_{A(q)} + b_{B(q)} + b1)   (64)
//   h2 = softplus(h1 @ W2 + b2)                     (32)
// where u = core@W1[0:64], a_n = lig_n@W1[64:128], b_n = lig_n@W1[128:192].
//
// Key idea: weights are wave-uniform -> SGPR-fed FMAs (v_fmac v,s,v), with
// lane = batch element. Per-batch precomputed T (13x64) lives in LDS as bf16.
// ---------------------------------------------------------------------------

constexpr int BPB       = 64;                 // batch elems per block (one per lane)
constexpr int NTHREADS  = 512;                // 8 waves
constexpr int T_STRIDE  = 1672;               // bytes per batch elem in T (13*128 + 8 pad; 418 words, %32==2 -> 2-way (free))
constexpr int X_OFF     = BPB * T_STRIDE;     // 107008
constexpr int X_STRIDE_W = 65;                // padded word stride of x row buffer
constexpr int Y_OFF     = X_OFF + 64 * X_STRIDE_W * 4;   // 123648
constexpr int LDS_BYTES = Y_OFF + 64 * 4;     // 123904 ( < 160 KiB )

// PAIRS i/j tables packed 3 bits per pair (15 pairs)
constexpr unsigned long long I_BITS =
  (0ull<<0)|(0ull<<3)|(0ull<<6)|(0ull<<9)|(0ull<<12)|
  (1ull<<15)|(1ull<<18)|(1ull<<21)|(1ull<<24)|
  (2ull<<27)|(2ull<<30)|(2ull<<33)|
  (3ull<<36)|(3ull<<39)|(4ull<<42);
constexpr unsigned long long J_BITS =
  (1ull<<0)|(2ull<<3)|(3ull<<6)|(4ull<<9)|(5ull<<12)|
  (2ull<<15)|(3ull<<18)|(4ull<<21)|(5ull<<24)|
  (3ull<<27)|(4ull<<30)|(5ull<<33)|
  (4ull<<36)|(5ull<<39)|(5ull<<42);

__device__ __forceinline__ float softplus_f(float x) {
  // stable: max(x,0) + log1p(exp(-|x|))
  float t = __expf(-fabsf(x));
  return fmaxf(x, 0.0f) + __logf(1.0f + t);
}

__device__ __forceinline__ uint32_t bf16_rn(float f) {
  union { float f; uint32_t u; } v; v.f = f;
  uint32_t u = v.u;
  return (u + 0x7fffu + ((u >> 16) & 1u)) >> 16;   // RNE, values are tame (no NaN/Inf)
}

__device__ __forceinline__ void unpk2(uint32_t d, float& lo, float& hi) {
  union { uint32_t u; float f; } a, b;
  a.u = d << 16; b.u = d & 0xffff0000u;
  lo = a.f; hi = b.f;
}

__global__ __launch_bounds__(NTHREADS, 2)
void tb_fused(const float* __restrict__ core, const float* __restrict__ ligs,
              const float* __restrict__ W1,   const float* __restrict__ b1,
              const float* __restrict__ W2,   const float* __restrict__ b2,
              const float* __restrict__ W3,   const float* __restrict__ b3,
              float* __restrict__ out)
{
  extern __shared__ char smem[];
  const int tid  = (int)threadIdx.x;
  const int lane = tid & 63;
  const int wv   = __builtin_amdgcn_readfirstlane(tid >> 6);  // force scalar wave id
  const int b0   = (int)blockIdx.x * BPB;
  const int k0   = wv * 8;                                    // this wave's k-slice

  float* xbuf = (float*)(smem + X_OFF);   // [64 d][65 words] transposed input row
  float* yred = (float*)(smem + Y_OFF);   // [64] per-batch-elem partial sums
  char*  Tb   = smem + lane * T_STRIDE;   // this lane's T block (13 rows x 128 B bf16)

  if (tid < 64) yred[tid] = 0.0f;

  const float* W1A = (const float*)__builtin_assume_aligned(W1, 16);
  const float* W2A = (const float*)__builtin_assume_aligned(W2, 16);

  // ------------------------- Phase A: build T ------------------------------
  // xr = 0 -> core (1 dot, row 0); xr = n+1 -> lig n (2 dots: rows 1+n, 7+n)
  #pragma unroll 1
  for (int xr = 0; xr < 7; ++xr) {
    __syncthreads();
    {
      // stage row transposed: thread (wave wv, lane) loads d=lane for b=wv*8+s
      // global read coalesced over lane(d); LDS write stride-65 -> conflict-free
      const float* src = (xr == 0)
          ? (core + (size_t)(b0 + wv * 8) * 64)
          : (ligs + ((size_t)(b0 + wv * 8) * 6 + (size_t)(xr - 1)) * 64);
      const int rs = (xr == 0) ? 64 : 384;
      #pragma unroll
      for (int s = 0; s < 8; ++s) {
        xbuf[lane * X_STRIDE_W + wv * 8 + s] = src[(size_t)s * rs + lane];
      }
    }
    __syncthreads();

    if (xr == 0) {
      float acc[8] = {0,0,0,0,0,0,0,0};
      #pragma unroll 2
      for (int dc = 0; dc < 8; ++dc) {
        float xv[8];
        #pragma unroll
        for (int dd = 0; dd < 8; ++dd)
          xv[dd] = xbuf[(dc * 8 + dd) * X_STRIDE_W + lane];   // lane-consecutive: free
        #pragma unroll
        for (int dd = 0; dd < 8; ++dd) {
          const float* wr = W1A + (dc * 8 + dd) * 64 + k0;    // uniform -> s_load
          #pragma unroll
          for (int e = 0; e < 8; ++e) acc[e] = fmaf(xv[dd], wr[e], acc[e]);
        }
      }
      uint32_t p0 = bf16_rn(acc[0]) | (bf16_rn(acc[1]) << 16);
      uint32_t p1 = bf16_rn(acc[2]) | (bf16_rn(acc[3]) << 16);
      uint32_t p2 = bf16_rn(acc[4]) | (bf16_rn(acc[5]) << 16);
      uint32_t p3 = bf16_rn(acc[6]) | (bf16_rn(acc[7]) << 16);
      uint2* dst = (uint2*)(Tb + 0 * 128 + wv * 16);          // 8-byte aligned
      dst[0] = make_uint2(p0, p1);
      dst[1] = make_uint2(p2, p3);
    } else {
      float accA[8] = {0,0,0,0,0,0,0,0};
      float accB[8] = {0,0,0,0,0,0,0,0};
      #pragma unroll 2
      for (int dc = 0; dc < 8; ++dc) {
        float xv[8];
        #pragma unroll
        for (int dd = 0; dd < 8; ++dd)
          xv[dd] = xbuf[(dc * 8 + dd) * X_STRIDE_W + lane];
        #pragma unroll
        for (int dd = 0; dd < 8; ++dd) {
          const int d = dc * 8 + dd;
          const float* wA = W1A + (64 + d) * 64 + k0;
          const float* wB = W1A + (128 + d) * 64 + k0;
          #pragma unroll
          for (int e = 0; e < 8; ++e) accA[e] = fmaf(xv[dd], wA[e], accA[e]);
          #pragma unroll
          for (int e = 0; e < 8; ++e) accB[e] = fmaf(xv[dd], wB[e], accB[e]);
        }
      }
      const int rowA = xr;        // 1 + (xr-1)
      const int rowB = 6 + xr;    // 7 + (xr-1)
      uint32_t pa0 = bf16_rn(accA[0]) | (bf16_rn(accA[1]) << 16);
      uint32_t pa1 = bf16_rn(accA[2]) | (bf16_rn(accA[3]) << 16);
      uint32_t pa2 = bf16_rn(accA[4]) | (bf16_rn(accA[5]) << 16);
      uint32_t pa3 = bf16_rn(accA[6]) | (bf16_rn(accA[7]) << 16);
      uint2* dA = (uint2*)(Tb + rowA * 128 + wv * 16);
      dA[0] = make_uint2(pa0, pa1);
      dA[1] = make_uint2(pa2, pa3);
      uint32_t pb0 = bf16_rn(accB[0]) | (bf16_rn(accB[1]) << 16);
      uint32_t pb1 = bf16_rn(accB[2]) | (bf16_rn(accB[3]) << 16);
      uint32_t pb2 = bf16_rn(accB[4]) | (bf16_rn(accB[5]) << 16);
      uint32_t pb3 = bf16_rn(accB[6]) | (bf16_rn(accB[7]) << 16);
      uint2* dB = (uint2*)(Tb + rowB * 128 + wv * 16);
      dB[0] = make_uint2(pb0, pb1);
      dB[1] = make_uint2(pb2, pb3);
    }
  }
  __syncthreads();

  // --------------------- Phase B: 30 MLP instances -------------------------
  // wave wv handles q in {wv, wv+8, wv+16, wv+24} intersect [0,30)
  float ylane = 0.0f;
  const float b3v = b3[0];
  #pragma unroll 1
  for (int t3 = 0; t3 < 4; ++t3) {
    const int q = wv + 8 * t3;
    if (q >= 30) break;                      // wave-uniform
    const int p  = q >> 1;
    const int iv = (int)((I_BITS >> (3 * p)) & 7ull);
    const int jv = (int)((J_BITS >> (3 * p)) & 7ull);
    const int An = (q & 1) ? jv : iv;        // ligand feeding W1[64:128]
    const int Bn = (q & 1) ? iv : jv;        // ligand feeding W1[128:192]
    const char* TbA = Tb + (1 + An) * 128;
    const char* TbB = Tb + (7 + Bn) * 128;

    float accm[32];
    #pragma unroll
    for (int m = 0; m < 32; ++m) accm[m] = 0.0f;

    #pragma unroll 4
    for (int c = 0; c < 16; ++c) {           // 4 k per chunk
      uint2 uu = *(const uint2*)(Tb  + c * 8);
      uint2 ua = *(const uint2*)(TbA + c * 8);
      uint2 ub = *(const uint2*)(TbB + c * 8);
      uint32_t du[2] = {uu.x, uu.y};
      uint32_t da[2] = {ua.x, ua.y};
      uint32_t db[2] = {ub.x, ub.y};
      #pragma unroll
      for (int g = 0; g < 2; ++g) {
        float u0, u1, a0, a1, v0, v1;
        unpk2(du[g], u0, u1);
        unpk2(da[g], a0, a1);
        unpk2(db[g], v0, v1);
        const int kk = c * 4 + g * 2;
        const float h0 = softplus_f(u0 + a0 + v0 + b1[kk]);
        const float h1 = softplus_f(u1 + a1 + v1 + b1[kk + 1]);
        const float* w0 = W2A + kk * 32;         // uniform -> s_load
        const float* w1 = W2A + (kk + 1) * 32;
        #pragma unroll
        for (int m = 0; m < 32; ++m) accm[m] = fmaf(h0, w0[m], accm[m]);
        #pragma unroll
        for (int m = 0; m < 32; ++m) accm[m] = fmaf(h1, w1[m], accm[m]);
      }
    }

    float yq = 0.0f;
    #pragma unroll
    for (int m = 0; m < 32; ++m) {
      const float h2 = softplus_f(accm[m] + b2[m]);
      yq = fmaf(h2, W3[m], yq);
    }
    ylane += yq + b3v;
  }

  atomicAdd(&yred[lane], ylane);   // combine partial q-sums across the 8 waves
  __syncthreads();
  if (tid < 64) out[b0 + tid] = 0.5f * yred[tid];
}

extern "C" void kernel_launch(void* const* d_in, const int* in_sizes, int n_in,
                              void* d_out, int out_size, void* d_ws, size_t ws_size,
                              hipStream_t stream) {
  const float* core = (const float*)d_in[0];
  const float* ligs = (const float*)d_in[1];
  const float* W1   = (const float*)d_in[2];
  const float* b1   = (const float*)d_in[3];
  const float* W2   = (const float*)d_in[4];
  const float* b2   = (const float*)d_in[5];
  const float* W3   = (const float*)d_in[6];
  const float* b3   = (const float*)d_in[7];
  float* out = (float*)d_out;

  const int B = in_sizes[0] / 64;           // 32768
  const int grid = B / BPB;                 // 512

  // >64 KiB dynamic LDS opt-in (CDNA4: 160 KiB per workgroup)
  (void)hipFuncSetAttribute((const void*)tb_fused,
                            hipFuncAttributeMaxDynamicSharedMemorySize, LDS_BYTES);

  tb_fused<<<dim3(grid), dim3(NTHREADS), LDS_BYTES, stream>>>(
      core, ligs, W1, b1, W2, b2, W3, b3, out);
}

// Round 2
// 275.699 us; speedup vs baseline: 1.1073x; 1.1073x over previous
//
#include <hip/hip_runtime.h>
#include <stdint.h>

// ---------------------------------------------------------------------------
// ThreeBodyLayer fused kernel v2 (MI355X / gfx950)
//
// out[b] = 0.5 * sum_{q=0..29} ( h2(q,b) @ W3 + b3 )
//   h1 = softplus(u_b + a_{A(q)} + b_{B(q)} + b1)   (64)
//   h2 = softplus(h1 @ W2 + b2)                     (32)
// with u = core@W1[0:64], a_n = lig_n@W1[64:128], b_n = lig_n@W1[128:192].
//
// v2 changes vs v1 (240us, VALUBusy 52%, occ 23%, FETCH 29GB):
//  - 1024-thread blocks (16 waves) -> 16 waves/CU instead of 8 (stall hiding)
//  - W2/b2/W3 staged in LDS, read via broadcast ds_read_b128 (no SGPR
//    pressure -> no VMEM/scratch demotion of the weight feeds)
//  - log2-domain softplus: T stored pre-scaled by log2(e), b1 folded into the
//    core row, ln2 folded into W3, b2 scaled by log2(e). softplus = 3 ops.
// ---------------------------------------------------------------------------

constexpr int   BPB       = 64;               // batch elems per block (lane = b)
constexpr int   NTHREADS  = 1024;             // 16 waves
constexpr int   T_STRIDE  = 1672;             // bytes per b in T (13*128 + 8 pad; 418 words %32==2 -> 2-way, free)
constexpr int   X_OFF     = BPB * T_STRIDE;             // 107008
constexpr int   XSW       = 65;                         // padded word stride of x staging
constexpr int   W2_OFF    = X_OFF + 64 * XSW * 4;       // 123648 (16B aligned)
constexpr int   C_OFF     = W2_OFF + 2048 * 4;          // 131840 (b2', W3')
constexpr int   Y_OFF     = C_OFF + 64 * 4;             // 132096
constexpr int   LDS_BYTES = Y_OFF + 64 * 4;             // 132352 < 160 KiB

constexpr float L2E = 1.4426950408889634f;    // log2(e)
constexpr float LN2 = 0.6931471805599453f;

// PAIRS i/j tables packed 3 bits per pair (15 pairs)
constexpr unsigned long long I_BITS =
  (0ull<<0)|(0ull<<3)|(0ull<<6)|(0ull<<9)|(0ull<<12)|
  (1ull<<15)|(1ull<<18)|(1ull<<21)|(1ull<<24)|
  (2ull<<27)|(2ull<<30)|(2ull<<33)|
  (3ull<<36)|(3ull<<39)|(4ull<<42);
constexpr unsigned long long J_BITS =
  (1ull<<0)|(2ull<<3)|(3ull<<6)|(4ull<<9)|(5ull<<12)|
  (2ull<<15)|(3ull<<18)|(4ull<<21)|(5ull<<24)|
  (3ull<<27)|(4ull<<30)|(5ull<<33)|
  (4ull<<36)|(5ull<<39)|(5ull<<42);

__device__ __forceinline__ uint32_t bf16_rn(float f) {
  union { float f; uint32_t u; } v; v.f = f;
  uint32_t u = v.u;
  return (u + 0x7fffu + ((u >> 16) & 1u)) >> 16;   // RNE; values are tame
}

__device__ __forceinline__ void unpk2(uint32_t d, float& lo, float& hi) {
  union { uint32_t u; float f; } a, b;
  a.u = d << 16; b.u = d & 0xffff0000u;
  lo = a.f; hi = b.f;
}

// softplus in log2 domain: returns log2(1 + exp2(s));  true softplus = ln2 * this
__device__ __forceinline__ float sp2(float s) {
  float t = __builtin_amdgcn_exp2f(s);
  return __builtin_amdgcn_logf(1.0f + t);          // v_log_f32 = log2
}

__global__ __launch_bounds__(NTHREADS, 4)
void tb_fused(const float* __restrict__ core, const float* __restrict__ ligs,
              const float* __restrict__ W1,   const float* __restrict__ b1,
              const float* __restrict__ W2,   const float* __restrict__ b2,
              const float* __restrict__ W3,   const float* __restrict__ b3,
              float* __restrict__ out)
{
  extern __shared__ char smem[];
  const int tid  = (int)threadIdx.x;
  const int lane = tid & 63;
  const int wv   = __builtin_amdgcn_readfirstlane(tid >> 6);  // 0..15, scalar
  const int b0   = (int)blockIdx.x * BPB;
  const int k0   = wv * 4;                                    // Phase A k-slice

  float* xbuf = (float*)(smem + X_OFF);   // [64 d][65 words] transposed input rows
  float* w2s  = (float*)(smem + W2_OFF);  // W2 (64x32), row-major
  float* cs   = (float*)(smem + C_OFF);   // [0..31]=b2*L2E  [32..63]=W3*ln2
  float* yred = (float*)(smem + Y_OFF);   // per-b partial sums
  char*  Tb   = smem + lane * T_STRIDE;   // this lane's T block (13 rows x 128B bf16)

  // one-time staging (covered by the first barrier of the xr loop)
  #pragma unroll
  for (int i = 0; i < 2; ++i) w2s[tid + i * 1024] = W2[tid + i * 1024];
  if (tid < 32)       cs[tid] = b2[tid] * L2E;
  else if (tid < 64)  cs[tid] = W3[tid - 32] * LN2;
  if (tid < 64)       yred[tid] = 0.0f;

  const float* W1A = (const float*)__builtin_assume_aligned(W1, 16);

  // ------------------------- Phase A: build T ------------------------------
  // xr = 0 -> core (row 0, +b1, *L2E); xr = n+1 -> lig n (rows 1+n and 7+n, *L2E)
  #pragma unroll 1
  for (int xr = 0; xr < 7; ++xr) {
    __syncthreads();
    {
      // stage transposed: thread t loads d=t&63 for 4 b's; coalesced global,
      // stride-65 LDS writes -> conflict-free
      const int d  = tid & 63;
      const int bq = tid >> 6;           // 0..15
      #pragma unroll
      for (int s = 0; s < 4; ++s) {
        const int b = bq + 16 * s;
        const size_t gidx = (xr == 0)
            ? ((size_t)(b0 + b) * 64 + d)
            : (((size_t)(b0 + b) * 6 + (size_t)(xr - 1)) * 64 + d);
        xbuf[d * XSW + b] = (xr == 0) ? core[gidx] : ligs[gidx];
      }
    }
    __syncthreads();

    if (xr == 0) {
      float acc[4];
      #pragma unroll
      for (int e = 0; e < 4; ++e) acc[e] = b1[k0 + e];      // fold b1 into row 0
      #pragma unroll 8
      for (int d = 0; d < 64; ++d) {
        const float xv = xbuf[d * XSW + lane];              // lane-consecutive
        const float* wr = W1A + d * 64 + k0;                // uniform -> s_load x4
        #pragma unroll
        for (int e = 0; e < 4; ++e) acc[e] = fmaf(xv, wr[e], acc[e]);
      }
      uint32_t p0 = bf16_rn(acc[0] * L2E) | (bf16_rn(acc[1] * L2E) << 16);
      uint32_t p1 = bf16_rn(acc[2] * L2E) | (bf16_rn(acc[3] * L2E) << 16);
      *(uint2*)(Tb + 0 * 128 + wv * 8) = make_uint2(p0, p1);
    } else {
      float accA[4] = {0, 0, 0, 0};
      float accB[4] = {0, 0, 0, 0};
      #pragma unroll 4
      for (int d = 0; d < 64; ++d) {
        const float xv = xbuf[d * XSW + lane];
        const float* wA = W1A + (64 + d) * 64 + k0;
        const float* wB = W1A + (128 + d) * 64 + k0;
        #pragma unroll
        for (int e = 0; e < 4; ++e) accA[e] = fmaf(xv, wA[e], accA[e]);
        #pragma unroll
        for (int e = 0; e < 4; ++e) accB[e] = fmaf(xv, wB[e], accB[e]);
      }
      uint32_t pa0 = bf16_rn(accA[0] * L2E) | (bf16_rn(accA[1] * L2E) << 16);
      uint32_t pa1 = bf16_rn(accA[2] * L2E) | (bf16_rn(accA[3] * L2E) << 16);
      *(uint2*)(Tb + xr * 128 + wv * 8) = make_uint2(pa0, pa1);        // row 1+n
      uint32_t pb0 = bf16_rn(accB[0] * L2E) | (bf16_rn(accB[1] * L2E) << 16);
      uint32_t pb1 = bf16_rn(accB[2] * L2E) | (bf16_rn(accB[3] * L2E) << 16);
      *(uint2*)(Tb + (6 + xr) * 128 + wv * 8) = make_uint2(pb0, pb1);  // row 7+n
    }
  }
  __syncthreads();

  // --------------------- Phase B: 30 MLP instances -------------------------
  // wave wv handles q in {wv, wv+16} intersect [0,30)
  float ylane = 0.0f;
  const float b3v = b3[0];
  #pragma unroll 1
  for (int t3 = 0; t3 < 2; ++t3) {
    const int q = wv + 16 * t3;
    if (q >= 30) break;                      // wave-uniform
    const int p  = q >> 1;
    const int iv = (int)((I_BITS >> (3 * p)) & 7ull);
    const int jv = (int)((J_BITS >> (3 * p)) & 7ull);
    const int An = (q & 1) ? jv : iv;        // ligand feeding W1[64:128]
    const int Bn = (q & 1) ? iv : jv;        // ligand feeding W1[128:192]
    const char* TbA = Tb + (1 + An) * 128;
    const char* TbB = Tb + (7 + Bn) * 128;

    float accm[32];
    #pragma unroll
    for (int m = 0; m < 32; ++m) accm[m] = 0.0f;

    #pragma unroll 2
    for (int c = 0; c < 16; ++c) {           // 4 k per chunk
      uint2 uu = *(const uint2*)(Tb  + c * 8);
      uint2 ua = *(const uint2*)(TbA + c * 8);
      uint2 ub = *(const uint2*)(TbB + c * 8);
      uint32_t du[2] = {uu.x, uu.y};
      uint32_t da[2] = {ua.x, ua.y};
      uint32_t db[2] = {ub.x, ub.y};
      #pragma unroll
      for (int g = 0; g < 2; ++g) {
        float u0, u1, a0, a1, v0, v1;
        unpk2(du[g], u0, u1);
        unpk2(da[g], a0, a1);
        unpk2(db[g], v0, v1);
        const int kk = c * 4 + g * 2;
        const float g0 = sp2(u0 + a0 + v0);  // log2-domain softplus (3 ops)
        const float g1 = sp2(u1 + a1 + v1);
        const float* w0 = w2s + kk * 32;         // uniform addr -> b128 broadcast
        const float* w1r = w2s + (kk + 1) * 32;
        #pragma unroll
        for (int m4 = 0; m4 < 8; ++m4) {
          const float4 wa = *(const float4*)(w0 + m4 * 4);
          accm[m4*4+0] = fmaf(g0, wa.x, accm[m4*4+0]);
          accm[m4*4+1] = fmaf(g0, wa.y, accm[m4*4+1]);
          accm[m4*4+2] = fmaf(g0, wa.z, accm[m4*4+2]);
          accm[m4*4+3] = fmaf(g0, wa.w, accm[m4*4+3]);
        }
        #pragma unroll
        for (int m4 = 0; m4 < 8; ++m4) {
          const float4 wb = *(const float4*)(w1r + m4 * 4);
          accm[m4*4+0] = fmaf(g1, wb.x, accm[m4*4+0]);
          accm[m4*4+1] = fmaf(g1, wb.y, accm[m4*4+1]);
          accm[m4*4+2] = fmaf(g1, wb.z, accm[m4*4+2]);
          accm[m4*4+3] = fmaf(g1, wb.w, accm[m4*4+3]);
        }
      }
    }

    // epilogue: h2 in log2 domain; ln2 folded into cs[32..63]
    float yq = 0.0f;
    #pragma unroll
    for (int m4 = 0; m4 < 8; ++m4) {
      const float4 bb = *(const float4*)(cs + m4 * 4);        // b2 * L2E
      const float4 ww = *(const float4*)(cs + 32 + m4 * 4);   // W3 * ln2
      yq = fmaf(sp2(accm[m4*4+0] + bb.x), ww.x, yq);
      yq = fmaf(sp2(accm[m4*4+1] + bb.y), ww.y, yq);
      yq = fmaf(sp2(accm[m4*4+2] + bb.z), ww.z, yq);
      yq = fmaf(sp2(accm[m4*4+3] + bb.w), ww.w, yq);
    }
    ylane += yq + b3v;
  }

  atomicAdd(&yred[lane], ylane);   // combine partial q-sums across the 16 waves
  __syncthreads();
  if (tid < 64) out[b0 + tid] = 0.5f * yred[tid];
}

extern "C" void kernel_launch(void* const* d_in, const int* in_sizes, int n_in,
                              void* d_out, int out_size, void* d_ws, size_t ws_size,
                              hipStream_t stream) {
  const float* core = (const float*)d_in[0];
  const float* ligs = (const float*)d_in[1];
  const float* W1   = (const float*)d_in[2];
  const float* b1   = (const float*)d_in[3];
  const float* W2   = (const float*)d_in[4];
  const float* b2   = (const float*)d_in[5];
  const float* W3   = (const float*)d_in[6];
  const float* b3   = (const float*)d_in[7];
  float* out = (float*)d_out;

  const int B = in_sizes[0] / 64;           // 32768
  const int grid = B / BPB;                 // 512

  (void)hipFuncSetAttribute((const void*)tb_fused,
                            hipFuncAttributeMaxDynamicSharedMemorySize, LDS_BYTES);

  tb_fused<<<dim3(grid), dim3(NTHREADS), LDS_BYTES, stream>>>(
      core, ligs, W1, b1, W2, b2, W3, b3, out);
}

// Round 3
// 146.777 us; speedup vs baseline: 2.0799x; 1.8784x over previous
//
#include <hip/hip_runtime.h>
#include <stdint.h>

// ---------------------------------------------------------------------------
// ThreeBodyLayer fused kernel v3 (MI355X / gfx950) — full-MFMA restructure
//
// Layer-1 (x@W1) and layer-2 (h1@W2) both become mfma_f32_16x16x32_bf16.
// T (13 x 64 per batch elem, log2-scaled pre-activations, b1 folded) in LDS
// as bf16. Softplus done in log2 domain: sp2(s) = log2(1+exp2(s)); all ln2 /
// log2(e) factors folded into Wt/W2t/b2v/w3v at staging time.
// ---------------------------------------------------------------------------

typedef __attribute__((ext_vector_type(8))) short bf16x8;
typedef __attribute__((ext_vector_type(4))) float f32x4;
typedef __attribute__((ext_vector_type(4))) unsigned int u32x4;

constexpr int   BPB      = 64;       // batch elems per block
constexpr int   NT       = 1024;     // 16 waves
constexpr int   T_STRIDE = 1680;     // bytes per b: 13*128 data + 16 pad; 16B-aligned; 420 words -> 2-way banks (free)
constexpr int   WT_RS    = 72;       // padded bf16 row stride (64 + 8)
constexpr int   WT_OFF   = BPB * T_STRIDE;          // 107520 : W1^T bf16 [192 rows][72]
constexpr int   W2T_OFF  = WT_OFF + 192 * WT_RS * 2;  // 135168 : W2^T bf16 [32 rows][72]
constexpr int   XB_OFF   = W2T_OFF + 32 * WT_RS * 2;  // 139776 : x-tile bf16 [64 rows][72]
constexpr int   Y_OFF    = XB_OFF + 64 * WT_RS * 2;   // 148992 : yred[64] f32
constexpr int   LDS_BYTES = Y_OFF + 256;              // 149248 < 160 KiB

constexpr float L2E = 1.4426950408889634f;
constexpr float LN2 = 0.6931471805599453f;

// PAIRS i/j packed 3 bits per pair (15 pairs)
constexpr unsigned long long I_BITS =
  (0ull<<0)|(0ull<<3)|(0ull<<6)|(0ull<<9)|(0ull<<12)|
  (1ull<<15)|(1ull<<18)|(1ull<<21)|(1ull<<24)|
  (2ull<<27)|(2ull<<30)|(2ull<<33)|
  (3ull<<36)|(3ull<<39)|(4ull<<42);
constexpr unsigned long long J_BITS =
  (1ull<<0)|(2ull<<3)|(3ull<<6)|(4ull<<9)|(5ull<<12)|
  (2ull<<15)|(3ull<<18)|(4ull<<21)|(5ull<<24)|
  (3ull<<27)|(4ull<<30)|(5ull<<33)|
  (4ull<<36)|(5ull<<39)|(5ull<<42);

__device__ __forceinline__ uint32_t bf16_rn(float f) {
  union { float f; uint32_t u; } v; v.f = f;
  uint32_t u = v.u;
  return (u + 0x7fffu + ((u >> 16) & 1u)) >> 16;   // RNE; values are tame
}

__device__ __forceinline__ void unpk2(uint32_t d, float& lo, float& hi) {
  union { uint32_t u; float f; } a, b;
  a.u = d << 16; b.u = d & 0xffff0000u;
  lo = a.f; hi = b.f;
}

// log2-domain softplus: log2(1 + exp2(s))
__device__ __forceinline__ float sp2(float s) {
  float t = __builtin_amdgcn_exp2f(s);
  return __builtin_amdgcn_logf(1.0f + t);          // v_log_f32 = log2
}

// fuse: two H1 bf16 elements from three packed-bf16 dwords (u, a, b rows)
__device__ __forceinline__ uint32_t sp2pair(uint32_t du, uint32_t da, uint32_t db) {
  float u0, u1, a0, a1, v0, v1;
  unpk2(du, u0, u1); unpk2(da, a0, a1); unpk2(db, v0, v1);
  float h0 = sp2(u0 + a0 + v0);
  float h1 = sp2(u1 + a1 + v1);
  return bf16_rn(h0) | (bf16_rn(h1) << 16);
}

__global__ __launch_bounds__(NT, 4)
void tb_fused(const float* __restrict__ core, const float* __restrict__ ligs,
              const float* __restrict__ W1,   const float* __restrict__ b1,
              const float* __restrict__ W2,   const float* __restrict__ b2,
              const float* __restrict__ W3,   const float* __restrict__ b3,
              float* __restrict__ out)
{
  extern __shared__ char smem[];
  const int tid  = (int)threadIdx.x;
  const int lane = tid & 63;
  const int ln   = lane & 15;        // fragment column index
  const int qd   = lane >> 4;        // fragment quad index
  const int wv   = __builtin_amdgcn_readfirstlane(tid >> 6);  // 0..15
  const int b0   = (int)blockIdx.x * BPB;

  float* yred = (float*)(smem + Y_OFF);

  // ---------------- one-time staging: W1^T, W2^T (bf16, scaled) ------------
  // Wt[(slab*64+n)*72 + d] = W1[slab*64+d][n] * L2E
  for (int idx = tid; idx < 12288; idx += NT) {
    const int d = idx >> 6, n = idx & 63;
    *(uint16_t*)(smem + WT_OFF + ((((d >> 6) * 64 + n) * WT_RS + (d & 63)) * 2)) =
        (uint16_t)bf16_rn(W1[idx] * L2E);
  }
  // W2t[m*72 + k] = W2[k][m] * ln2 * L2E
  for (int idx = tid; idx < 2048; idx += NT) {
    const int k = idx >> 5, m = idx & 31;
    *(uint16_t*)(smem + W2T_OFF + ((m * WT_RS + k) * 2)) =
        (uint16_t)bf16_rn(W2[idx] * (LN2 * L2E));
  }
  if (tid < 64) yred[tid] = 0.0f;
  __syncthreads();

  // per-wave register copies of the W2 B-fragments (shared by all q)
  bf16x8 W2f[2][2];
  #pragma unroll
  for (int nt = 0; nt < 2; ++nt)
    #pragma unroll
    for (int ks = 0; ks < 2; ++ks)
      W2f[nt][ks] = *(const bf16x8*)(smem + W2T_OFF +
          (((nt * 16 + ln) * WT_RS + ks * 32 + qd * 8) * 2));

  // per-lane epilogue constants
  float b2v[2], w3v[2];
  #pragma unroll
  for (int nt = 0; nt < 2; ++nt) {
    b2v[nt] = b2[nt * 16 + ln] * L2E;
    w3v[nt] = W3[nt * 16 + ln] * LN2;
  }

  // ---------------- Phase 1: build T via MFMA ------------------------------
  // unit = (slab, mt, nt, trow): C = xb(16b x 64d) @ Wt-slab(64d x 16n)
  auto p1_unit = [&](int slab, int mt, int nt, int trow, bool add_b1) {
    f32x4 c = {0.f, 0.f, 0.f, 0.f};
    #pragma unroll
    for (int ks = 0; ks < 2; ++ks) {
      bf16x8 A = *(const bf16x8*)(smem + XB_OFF +
          (((mt * 16 + ln) * WT_RS + ks * 32 + qd * 8) * 2));
      bf16x8 Bf = *(const bf16x8*)(smem + WT_OFF +
          (((slab * 64 + nt * 16 + ln) * WT_RS + ks * 32 + qd * 8) * 2));
      c = __builtin_amdgcn_mfma_f32_16x16x32_bf16(A, Bf, c, 0, 0, 0);
    }
    const float bias = add_b1 ? b1[nt * 16 + ln] * L2E : 0.0f;
    #pragma unroll
    for (int reg = 0; reg < 4; ++reg) {
      const int b = mt * 16 + qd * 4 + reg;             // C row = m (batch-local)
      *(uint16_t*)(smem + (size_t)b * T_STRIDE + trow * 128 + (nt * 16 + ln) * 2) =
          (uint16_t)bf16_rn(c[reg] + bias);
    }
  };

  #pragma unroll 1
  for (int xr = 0; xr < 7; ++xr) {
    if (tid < 512) {                                    // stage 64x64 f32 -> bf16 LDS
      const int b = tid >> 3, d0 = (tid & 7) * 8;
      const float* src = (xr == 0)
          ? (core + (size_t)(b0 + b) * 64 + d0)
          : (ligs + ((size_t)(b0 + b) * 6 + (size_t)(xr - 1)) * 64 + d0);
      const float4 f0 = *(const float4*)(src);
      const float4 f1 = *(const float4*)(src + 4);
      u32x4 pk;
      pk.x = bf16_rn(f0.x) | (bf16_rn(f0.y) << 16);
      pk.y = bf16_rn(f0.z) | (bf16_rn(f0.w) << 16);
      pk.z = bf16_rn(f1.x) | (bf16_rn(f1.y) << 16);
      pk.w = bf16_rn(f1.z) | (bf16_rn(f1.w) << 16);
      *(u32x4*)(smem + XB_OFF + ((b * WT_RS + d0) * 2)) = pk;
    }
    __syncthreads();

    if (xr == 0) {
      p1_unit(0, wv >> 2, wv & 3, 0, true);             // 16 units over 16 waves
    } else {
      p1_unit(1, wv >> 2, wv & 3, xr, false);           // 'a' row: T[1 + (xr-1)]
      p1_unit(2, wv >> 2, wv & 3, 6 + xr, false);       // 'b' row: T[7 + (xr-1)]
    }
    __syncthreads();                                    // protect xb reuse
  }

  // ---------------- Phase 2: 30 q x 4 m-tiles = 120 units ------------------
  float yacc[16];
  #pragma unroll
  for (int i = 0; i < 16; ++i) yacc[i] = 0.0f;

  #pragma unroll 1
  for (int u = wv; u < 120; u += 16) {
    const int q  = u >> 2;
    const int mt = u & 3;
    const int p  = q >> 1;
    const int iv = (int)((I_BITS >> (3 * p)) & 7ull);
    const int jv = (int)((J_BITS >> (3 * p)) & 7ull);
    const int An = (q & 1) ? jv : iv;
    const int Bn = (q & 1) ? iv : jv;

    const char* Tb = smem + (size_t)(mt * 16 + ln) * T_STRIDE;
    const int rA = (1 + An) * 128;
    const int rB = (7 + Bn) * 128;

    f32x4 c0 = {0.f, 0.f, 0.f, 0.f};
    f32x4 c1 = {0.f, 0.f, 0.f, 0.f};
    #pragma unroll
    for (int ks = 0; ks < 2; ++ks) {
      const int koff = (ks * 32 + qd * 8) * 2;
      const u32x4 du = *(const u32x4*)(Tb + koff);            // u row (trow 0)
      const u32x4 da = *(const u32x4*)(Tb + rA + koff);
      const u32x4 db = *(const u32x4*)(Tb + rB + koff);
      union { u32x4 u; bf16x8 v; } A;
      A.u.x = sp2pair(du.x, da.x, db.x);
      A.u.y = sp2pair(du.y, da.y, db.y);
      A.u.z = sp2pair(du.z, da.z, db.z);
      A.u.w = sp2pair(du.w, da.w, db.w);
      c0 = __builtin_amdgcn_mfma_f32_16x16x32_bf16(A.v, W2f[0][ks], c0, 0, 0, 0);
      c1 = __builtin_amdgcn_mfma_f32_16x16x32_bf16(A.v, W2f[1][ks], c1, 0, 0, 0);
    }
    #pragma unroll
    for (int reg = 0; reg < 4; ++reg) {
      float y = sp2(c0[reg] + b2v[0]) * w3v[0]
              + sp2(c1[reg] + b2v[1]) * w3v[1];
      yacc[mt * 4 + reg] += y;
    }
  }

  // reduce over the 16 fragment columns (lanes ln=0..15 within each quad-group)
  #pragma unroll
  for (int i = 0; i < 16; ++i) {
    float v = yacc[i];
    v += __shfl_xor(v, 1);
    v += __shfl_xor(v, 2);
    v += __shfl_xor(v, 4);
    v += __shfl_xor(v, 8);
    yacc[i] = v;
  }
  if (ln == 0) {
    #pragma unroll
    for (int mt = 0; mt < 4; ++mt)
      #pragma unroll
      for (int reg = 0; reg < 4; ++reg)
        atomicAdd(&yred[mt * 16 + qd * 4 + reg], yacc[mt * 4 + reg]);
  }
  __syncthreads();
  if (tid < 64) out[b0 + tid] = 0.5f * yred[tid] + 15.0f * b3[0];
}

extern "C" void kernel_launch(void* const* d_in, const int* in_sizes, int n_in,
                              void* d_out, int out_size, void* d_ws, size_t ws_size,
                              hipStream_t stream) {
  const float* core = (const float*)d_in[0];
  const float* ligs = (const float*)d_in[1];
  const float* W1   = (const float*)d_in[2];
  const float* b1   = (const float*)d_in[3];
  const float* W2   = (const float*)d_in[4];
  const float* b2   = (const float*)d_in[5];
  const float* W3   = (const float*)d_in[6];
  const float* b3   = (const float*)d_in[7];
  float* out = (float*)d_out;

  const int B = in_sizes[0] / 64;           // 32768
  const int grid = B / BPB;                 // 512

  (void)hipFuncSetAttribute((const void*)tb_fused,
                            hipFuncAttributeMaxDynamicSharedMemorySize, LDS_BYTES);

  tb_fused<<<dim3(grid), dim3(NT), LDS_BYTES, stream>>>(
      core, ligs, W1, b1, W2, b2, W3, b3, out);
}

// Round 5
// 126.856 us; speedup vs baseline: 2.4065x; 1.1570x over previous
//
#include <hip/hip_runtime.h>
#include <hip/hip_fp16.h>
#include <stdint.h>

// ---------------------------------------------------------------------------
// ThreeBodyLayer fused kernel v4b (MI355X / gfx950)
//
// All-f16 MFMA pipeline. T (13 x 64 per batch elem, log2-scaled
// pre-activations, b1 folded) lives in LDS as f16. Softplus in log2 domain:
// h1 = log2(1+exp2(s)) = log2(e)*softplus(z), computed entirely in packed
// f16 (2 hadd2 + h2exp2 + hadd2 + h2log2 per TWO h1 values), feeding
// mfma_f32_16x16x32_f16 directly. Scale algebra: T,W1 carry log2(e); W2
// carries ln2*log2(e)=1; b2*log2(e); W3*ln2.
//
// v4b vs v4: fix cvt_pkrtz return-type mismatch (__fp16 vec2 vs _Float16
// vec2) via union bit-cast.
// ---------------------------------------------------------------------------

typedef __attribute__((ext_vector_type(8))) _Float16 f16x8;
typedef __attribute__((ext_vector_type(2))) __fp16   fp16v2;   // cvt_pkrtz ret type
typedef __attribute__((ext_vector_type(4))) float    f32x4;
typedef __attribute__((ext_vector_type(4))) unsigned int u32x4;

constexpr int   BPB      = 64;        // batch elems per block
constexpr int   NT       = 1024;      // 16 waves
constexpr int   T_STRIDE = 1680;      // bytes per b: 13*128 + 16 pad (16B aligned)
constexpr int   WT_RS    = 72;        // padded f16 row stride (64 + 8)
constexpr int   WT_OFF   = BPB * T_STRIDE;            // 107520 : W1^T f16 [192][72]
constexpr int   W2T_OFF  = WT_OFF + 192 * WT_RS * 2;  // 135168 : W2^T f16 [32][72]
constexpr int   Y_OFF    = W2T_OFF + 32 * WT_RS * 2;  // 139776 : yred[64] f32
constexpr int   LDS_BYTES = Y_OFF + 256;              // 140032 < 160 KiB

constexpr float L2E = 1.4426950408889634f;
constexpr float LN2 = 0.6931471805599453f;

// PAIRS i/j packed 3 bits per pair (15 pairs)
constexpr unsigned long long I_BITS =
  (0ull<<0)|(0ull<<3)|(0ull<<6)|(0ull<<9)|(0ull<<12)|
  (1ull<<15)|(1ull<<18)|(1ull<<21)|(1ull<<24)|
  (2ull<<27)|(2ull<<30)|(2ull<<33)|
  (3ull<<36)|(3ull<<39)|(4ull<<42);
constexpr unsigned long long J_BITS =
  (1ull<<0)|(2ull<<3)|(3ull<<6)|(4ull<<9)|(5ull<<12)|
  (2ull<<15)|(3ull<<18)|(4ull<<21)|(5ull<<24)|
  (3ull<<27)|(4ull<<30)|(5ull<<33)|
  (4ull<<36)|(5ull<<39)|(5ull<<42);

// f32 log2-domain softplus (epilogue): log2(1 + exp2(s))
__device__ __forceinline__ float sp2(float s) {
  float t = __builtin_amdgcn_exp2f(s);
  return __builtin_amdgcn_logf(1.0f + t);          // v_log_f32 = log2
}

// packed-f16 log2-domain softplus for TWO h1 values
__device__ __forceinline__ __half2 h1pair(__half2 u, __half2 a, __half2 b,
                                          __half2 one2) {
  __half2 s = __hadd2(__hadd2(u, a), b);
  __half2 t = h2exp2(s);                           // |s| <~ 12 -> exp2 <= 4096, safe in f16
  return h2log2(__hadd2(one2, t));
}

__global__ __launch_bounds__(NT, 4)
void tb_fused(const float* __restrict__ core, const float* __restrict__ ligs,
              const float* __restrict__ W1,   const float* __restrict__ b1,
              const float* __restrict__ W2,   const float* __restrict__ b2,
              const float* __restrict__ W3,   const float* __restrict__ b3,
              float* __restrict__ out)
{
  extern __shared__ char smem[];
  const int tid  = (int)threadIdx.x;
  const int lane = tid & 63;
  const int ln   = lane & 15;        // fragment column
  const int qd   = lane >> 4;        // fragment quad
  const int wv   = __builtin_amdgcn_readfirstlane(tid >> 6);  // 0..15
  const int qr   = wv >> 2;          // 0..3
  const int mtw  = wv & 3;           // this wave's fixed m-tile
  const int b0   = (int)blockIdx.x * BPB;

  float* yred = (float*)(smem + Y_OFF);

  // ------------- one-time staging: W1^T, W2^T (f16, scaled) ---------------
  // Wt[(slab*64+n)*72 + d] = W1[slab*64+d][n] * L2E
  #pragma unroll 4
  for (int idx = tid; idx < 12288; idx += NT) {
    const int d = idx >> 6, n = idx & 63;
    *(uint16_t*)(smem + WT_OFF + ((((d >> 6) * 64 + n) * WT_RS + (d & 63)) * 2)) =
        __half_as_ushort(__float2half(W1[idx] * L2E));
  }
  // W2t[m*72 + k] = W2[k][m]   (ln2*log2e = 1)
  #pragma unroll
  for (int idx = tid; idx < 2048; idx += NT) {
    const int k = idx >> 5, m = idx & 31;
    *(uint16_t*)(smem + W2T_OFF + ((m * WT_RS + k) * 2)) =
        __half_as_ushort(__float2half(W2[idx]));
  }
  if (tid < 64) yred[tid] = 0.0f;
  __syncthreads();                                  // barrier #1

  // ------------- Phase 1: build T via MFMA, A-frags from global -----------
  // wave (qr,mtw) handles xr in {qr, qr+4} (xr=7 skipped)
  #pragma unroll 1
  for (int rep = 0; rep < 2; ++rep) {
    const int xr = qr + rep * 4;
    if (xr >= 7) break;                             // wave-uniform
    const float* src = (xr == 0)
        ? (core + (size_t)(b0 + mtw * 16 + ln) * 64)
        : (ligs + ((size_t)(b0 + mtw * 16 + ln) * 6 + (size_t)(xr - 1)) * 64);

    union AF { f16x8 v; fp16v2 p[4]; } Afr[2];
    #pragma unroll
    for (int ks = 0; ks < 2; ++ks) {
      const float4 f0 = *(const float4*)(src + ks * 32 + qd * 8);
      const float4 f1 = *(const float4*)(src + ks * 32 + qd * 8 + 4);
      Afr[ks].p[0] = __builtin_amdgcn_cvt_pkrtz(f0.x, f0.y);
      Afr[ks].p[1] = __builtin_amdgcn_cvt_pkrtz(f0.z, f0.w);
      Afr[ks].p[2] = __builtin_amdgcn_cvt_pkrtz(f1.x, f1.y);
      Afr[ks].p[3] = __builtin_amdgcn_cvt_pkrtz(f1.z, f1.w);
    }

    const int sl_lo = (xr == 0) ? 0 : 1;
    const int sl_hi = (xr == 0) ? 0 : 2;
    #pragma unroll 1
    for (int sl = sl_lo; sl <= sl_hi; ++sl) {
      const int trow = (xr == 0) ? 0 : ((sl == 1) ? xr : 6 + xr);
      #pragma unroll
      for (int nt = 0; nt < 4; ++nt) {
        f32x4 c = {0.f, 0.f, 0.f, 0.f};
        #pragma unroll
        for (int ks = 0; ks < 2; ++ks) {
          f16x8 Bf = *(const f16x8*)(smem + WT_OFF +
              (((sl * 64 + nt * 16 + ln) * WT_RS + ks * 32 + qd * 8) * 2));
          c = __builtin_amdgcn_mfma_f32_16x16x32_f16(Afr[ks].v, Bf, c, 0, 0, 0);
        }
        const float bias = (xr == 0) ? b1[nt * 16 + ln] * L2E : 0.0f;
        #pragma unroll
        for (int reg = 0; reg < 4; ++reg) {
          const int b = mtw * 16 + qd * 4 + reg;    // C row=m=batch-local
          *(uint16_t*)(smem + (size_t)b * T_STRIDE + trow * 128 + (nt * 16 + ln) * 2) =
              __half_as_ushort(__float2half(c[reg] + bias));
        }
      }
    }
  }
  __syncthreads();                                  // barrier #2

  // ------------- Phase 2: q = qr + 4*t, fixed m-tile mtw ------------------
  // W2 B-fragments in registers (read once, after barrier #1 staging)
  f16x8 W2f[2][2];
  #pragma unroll
  for (int nt = 0; nt < 2; ++nt)
    #pragma unroll
    for (int ks = 0; ks < 2; ++ks)
      W2f[nt][ks] = *(const f16x8*)(smem + W2T_OFF +
          (((nt * 16 + ln) * WT_RS + ks * 32 + qd * 8) * 2));

  float b2v[2], w3v[2];
  #pragma unroll
  for (int nt = 0; nt < 2; ++nt) {
    b2v[nt] = b2[nt * 16 + ln] * L2E;
    w3v[nt] = W3[nt * 16 + ln] * LN2;
  }

  const __half2 one2 = __float2half2_rn(1.0f);
  const char* Tb  = smem + (size_t)(mtw * 16 + ln) * T_STRIDE;
  const int koff  = qd * 16;                        // bytes: qd*8 halves

  float yacc[4] = {0.f, 0.f, 0.f, 0.f};

  #pragma unroll 2
  for (int t3 = 0; t3 < 8; ++t3) {
    const int q = qr + 4 * t3;
    if (q >= 30) break;                             // wave-uniform (only t3=7)
    const int p  = q >> 1;
    const int iv = (int)((I_BITS >> (3 * p)) & 7ull);
    const int jv = (int)((J_BITS >> (3 * p)) & 7ull);
    const int An = (q & 1) ? jv : iv;
    const int Bn = (q & 1) ? iv : jv;
    const char* TA = Tb + (1 + An) * 128;
    const char* TB = Tb + (7 + Bn) * 128;

    union U4 { u32x4 u; __half2 h[4]; };
    U4 du0, da0, db0, du1, da1, db1;
    du0.u = *(const u32x4*)(Tb + koff);
    da0.u = *(const u32x4*)(TA + koff);
    db0.u = *(const u32x4*)(TB + koff);
    du1.u = *(const u32x4*)(Tb + 64 + koff);
    da1.u = *(const u32x4*)(TA + 64 + koff);
    db1.u = *(const u32x4*)(TB + 64 + koff);

    union { f16x8 v; __half2 h[4]; } A0, A1;
    #pragma unroll
    for (int w = 0; w < 4; ++w) A0.h[w] = h1pair(du0.h[w], da0.h[w], db0.h[w], one2);
    #pragma unroll
    for (int w = 0; w < 4; ++w) A1.h[w] = h1pair(du1.h[w], da1.h[w], db1.h[w], one2);

    f32x4 c0 = {0.f, 0.f, 0.f, 0.f};
    f32x4 c1 = {0.f, 0.f, 0.f, 0.f};
    c0 = __builtin_amdgcn_mfma_f32_16x16x32_f16(A0.v, W2f[0][0], c0, 0, 0, 0);
    c0 = __builtin_amdgcn_mfma_f32_16x16x32_f16(A1.v, W2f[0][1], c0, 0, 0, 0);
    c1 = __builtin_amdgcn_mfma_f32_16x16x32_f16(A0.v, W2f[1][0], c1, 0, 0, 0);
    c1 = __builtin_amdgcn_mfma_f32_16x16x32_f16(A1.v, W2f[1][1], c1, 0, 0, 0);

    #pragma unroll
    for (int reg = 0; reg < 4; ++reg) {
      yacc[reg] += sp2(c0[reg] + b2v[0]) * w3v[0]
                 + sp2(c1[reg] + b2v[1]) * w3v[1];
    }
  }

  // reduce over the 16 fragment columns (ln) inside each quad group
  #pragma unroll
  for (int reg = 0; reg < 4; ++reg) {
    float v = yacc[reg];
    v += __shfl_xor(v, 1);
    v += __shfl_xor(v, 2);
    v += __shfl_xor(v, 4);
    v += __shfl_xor(v, 8);
    yacc[reg] = v;
  }
  if (ln == 0) {
    #pragma unroll
    for (int reg = 0; reg < 4; ++reg)
      atomicAdd(&yred[mtw * 16 + qd * 4 + reg], yacc[reg]);
  }
  __syncthreads();
  if (tid < 64) out[b0 + tid] = 0.5f * yred[tid] + 15.0f * b3[0];
}

extern "C" void kernel_launch(void* const* d_in, const int* in_sizes, int n_in,
                              void* d_out, int out_size, void* d_ws, size_t ws_size,
                              hipStream_t stream) {
  const float* core = (const float*)d_in[0];
  const float* ligs = (const float*)d_in[1];
  const float* W1   = (const float*)d_in[2];
  const float* b1   = (const float*)d_in[3];
  const float* W2   = (const float*)d_in[4];
  const float* b2   = (const float*)d_in[5];
  const float* W3   = (const float*)d_in[6];
  const float* b3   = (const float*)d_in[7];
  float* out = (float*)d_out;

  const int B = in_sizes[0] / 64;           // 32768
  const int grid = B / BPB;                 // 512

  (void)hipFuncSetAttribute((const void*)tb_fused,
                            hipFuncAttributeMaxDynamicSharedMemorySize, LDS_BYTES);

  tb_fused<<<dim3(grid), dim3(NT), LDS_BYTES, stream>>>(
      core, ligs, W1, b1, W2, b2, W3, b3, out);
}